// Round 4
// baseline (165.166 us; speedup 1.0000x reference)
//
#include <hip/hip_runtime.h>
#include <hip/hip_bf16.h>

// Problem constants (reference: B=64, Z=512, H=W=32 -> N=1024, Q=1)
#define B_ 64
#define Z_ 512
#define N_ 1024
#define LAM 1e-3f
#define NQ 32       // column-slabs per batch sample (one block each)
#define NC 32       // pixel columns per block = N_/NQ
#define TH 512      // threads per block
#define WS_XH (B_ * NQ * Z_)        // floats: xh partials
#define WS_G  (B_ * NQ)             // floats: g partials
// then B_ uint32 arrival counters

// Block (b, nq): owns pixel columns [nq*32, nq*32+32) of sample b.
// Slab x[b, :, cols] (512 z x 32 cols = 64 KB) lives in REGISTERS:
//   thread t: jg = t&7 (4-col group), zr = t>>3 in [0,64); v[k] = float4 at
//   z = zr + 64k, k = 0..7. All 8 loads independent, issued upfront.
// phase A: s[c] = sum_z W[z] x[z,c]; per-thread partials, shfl_xor(8,16,32)
//   wave-reduce, 8x32 LDS partials, 32-thread final -> h = sigmoid(s)
// phase B: xh[z] = sum_c x[z,c] h[c]; register FMA, shfl_xor(1,2,4) over jg,
//   lane jg==0 stores the per-block partial to ws.
// FUSED FINALIZE (last-block-done per sample): ticket = atomicAdd(cnt[b]);
//   ticket==NQ-1 block reduces the 32 partials + divides by (g+LAM) -> out.
//   Release = __syncthreads (drains stores to L2) + __threadfence (L2 wb past
//   non-coherent XCD L2); acquire = __threadfence in finalizer (L2 inv).
__global__ __launch_bounds__(TH, 8) void elm_k1(
    const float* __restrict__ x, const float* __restrict__ Wh,
    float* __restrict__ pxh, float* __restrict__ gws,
    unsigned int* __restrict__ cnt, float* __restrict__ out) {
  __shared__ float part[8][NC];   // per-wave s partials (1 KB)
  __shared__ float h_lds[NC];
  __shared__ unsigned int tick;
  __shared__ float ginv;

  const int t   = threadIdx.x;
  const int bid = blockIdx.x;
  const int b   = bid >> 5;
  const int nq  = bid & 31;
  const int jg  = t & 7;          // column group (4 cols)
  const int zr  = t >> 3;         // z residue [0,64)
  const int wv  = t >> 6;         // wave id [0,8)
  const int ln  = t & 63;

  const float* xp = x + (size_t)b * (Z_ * N_) + (size_t)zr * N_ + (nq * NC + jg * 4);

  float4 v[8];
#pragma unroll
  for (int k = 0; k < 8; ++k)
    v[k] = *reinterpret_cast<const float4*>(xp + (size_t)(64 * k) * N_);

  float w[8];
#pragma unroll
  for (int k = 0; k < 8; ++k) w[k] = Wh[zr + 64 * k];

  // ---- phase A ----
  float sp[4];
#pragma unroll
  for (int i = 0; i < 4; ++i) {
    float s = 0.f;
#pragma unroll
    for (int k = 0; k < 8; ++k) s += w[k] * reinterpret_cast<const float*>(&v[k])[i];
    s += __shfl_xor(s, 8);
    s += __shfl_xor(s, 16);
    s += __shfl_xor(s, 32);
    sp[i] = s;
  }
  if (ln < 8) {
#pragma unroll
    for (int i = 0; i < 4; ++i) part[wv][ln * 4 + i] = sp[i];
  }
  __syncthreads();

  if (t < NC) {
    float s = 0.f;
#pragma unroll
    for (int w8 = 0; w8 < 8; ++w8) s += part[w8][t];
    const float h = 1.f / (1.f + __expf(-s));
    h_lds[t] = h;
    float q = h * h;               // lanes 0..31 of wave 0
    q += __shfl_xor(q, 1);
    q += __shfl_xor(q, 2);
    q += __shfl_xor(q, 4);
    q += __shfl_xor(q, 8);
    q += __shfl_xor(q, 16);
    if (t == 0) gws[bid] = q;
  }
  __syncthreads();

  // ---- phase B ----
  float acc[8] = {0.f, 0.f, 0.f, 0.f, 0.f, 0.f, 0.f, 0.f};
#pragma unroll
  for (int i = 0; i < 4; ++i) {
    const float h = h_lds[jg * 4 + i];
#pragma unroll
    for (int k = 0; k < 8; ++k) acc[k] += h * reinterpret_cast<const float*>(&v[k])[i];
  }
#pragma unroll
  for (int k = 0; k < 8; ++k) {
    float a = acc[k];
    a += __shfl_xor(a, 1);
    a += __shfl_xor(a, 2);
    a += __shfl_xor(a, 4);
    if (jg == 0) pxh[(size_t)bid * Z_ + zr + 64 * k] = a;
  }

  // ---- arrival + fused finalize (last block of this sample) ----
  __syncthreads();                 // all waves' gws/pxh stores drained to L2
  if (t == 0) {
    __threadfence();               // release: write back past XCD-local L2
    tick = atomicAdd(&cnt[b], 1u);
  }
  __syncthreads();
  if (tick == NQ - 1) {
    __threadfence();               // acquire: invalidate stale L1/L2 lines
    if (t < NQ) {
      float g = gws[b * NQ + t];
      g += __shfl_xor(g, 1);
      g += __shfl_xor(g, 2);
      g += __shfl_xor(g, 4);
      g += __shfl_xor(g, 8);
      g += __shfl_xor(g, 16);
      if (t == 0) ginv = 1.f / (g + LAM);
    }
    __syncthreads();
    float s = 0.f;                 // TH == Z_: one output z per thread
#pragma unroll
    for (int q2 = 0; q2 < NQ; ++q2) s += pxh[((size_t)b * NQ + q2) * Z_ + t];
    out[b * Z_ + t] = s * ginv;
  }
}

extern "C" void kernel_launch(void* const* d_in, const int* in_sizes, int n_in,
                              void* d_out, int out_size, void* d_ws, size_t ws_size,
                              hipStream_t stream) {
  const float* x  = (const float*)d_in[0];
  const float* Wh = (const float*)d_in[1];
  float* out = (float*)d_out;
  float* pxh = (float*)d_ws;                       // 4 MB
  float* gws = (float*)d_ws + WS_XH;               // 8 KB
  unsigned int* cnt = (unsigned int*)((float*)d_ws + WS_XH + WS_G);  // 256 B

  hipMemsetAsync(cnt, 0, B_ * sizeof(unsigned int), stream);
  elm_k1<<<dim3(B_ * NQ), dim3(TH), 0, stream>>>(x, Wh, pxh, gws, cnt, out);
}

// Round 5
// 45.084 us; speedup vs baseline: 3.6635x; 3.6635x over previous
//
#include <hip/hip_runtime.h>
#include <hip/hip_bf16.h>

// Problem constants (reference: B=64, Z=512, H=W=32 -> N=1024, Q=1)
#define B_ 64
#define Z_ 512
#define N_ 1024
#define LAM 1e-3f
#define PB 8        // blocks per sample (each owns 128 columns)
#define NSL 4       // 32-col slabs per block
#define NC 32       // columns per slab
#define TH 512
#define WS_XH (B_ * PB * Z_)   // floats: xh partials (1 MB)
#define WS_G  (B_ * PB)        // floats: g partials

// LDS-only barrier: orders ds_write -> ds_read across the block WITHOUT
// draining vmcnt -- global loads stay in flight across it (the R3 limiter
// was __syncthreads' s_waitcnt vmcnt(0) before s_barrier). sched_barrier(0)
// pins ordering per guide rule #18.
__device__ __forceinline__ void lds_barrier() {
  asm volatile("s_waitcnt lgkmcnt(0)" ::: "memory");
  __builtin_amdgcn_sched_barrier(0);
  __builtin_amdgcn_s_barrier();
  __builtin_amdgcn_sched_barrier(0);
}

// Block (b, p): owns columns [p*128, p*128+128) of sample b as 4 slabs of 32.
// Per slab (register-resident, 8 float4/thread: jg=t&7 col-group, zr=t>>3,
// z = zr+64k):
//   phase A: s[c] = sum_z W[z] x[z,c]  (shfl_xor 8/16/32 + LDS partials)
//   h = sigmoid(s) by wave 0, g += sum h^2
//   phase B: acc[k] += h[c]*x[z,c]  (persistent accumulator across slabs)
// Slab s+1's loads are issued BEFORE slab s is consumed (va/vb double
// buffer); barriers are lgkm-only so the load queue never drains.
// End: shfl-reduce acc over jg, store per-block partial + g. No atomics.
__global__ __launch_bounds__(TH, 4) void elm_k1(
    const float* __restrict__ x, const float* __restrict__ Wh,
    float* __restrict__ pxh, float* __restrict__ gws) {
  __shared__ float part[8][NC];   // per-wave phase-A partials (1 KB)
  __shared__ float h_lds[NC];

  const int t   = threadIdx.x;
  const int blk = blockIdx.x;
  const int b   = blk >> 3;
  const int p   = blk & 7;
  const int jg  = t & 7;          // column group (4 cols) within slab
  const int zr  = t >> 3;         // z residue [0,64)
  const int wv  = t >> 6;         // wave id [0,8)
  const int ln  = t & 63;

  const float* xp = x + (size_t)b * (Z_ * N_) + (size_t)zr * N_ + (p * 128 + jg * 4);

  float w[8];
#pragma unroll
  for (int k = 0; k < 8; ++k) w[k] = Wh[zr + 64 * k];

  float acc[8] = {0.f, 0.f, 0.f, 0.f, 0.f, 0.f, 0.f, 0.f};
  float gacc = 0.f;
  float4 va[8], vb[8];

#define LOADS(V, S)                                                          \
  _Pragma("unroll") for (int k = 0; k < 8; ++k)                              \
      V[k] = *reinterpret_cast<const float4*>(xp + (size_t)(64 * k) * N_ + (S) * NC);

#define PROC(V)                                                              \
  do {                                                                       \
    float sp[4];                                                             \
    _Pragma("unroll") for (int i = 0; i < 4; ++i) {                          \
      float s_ = 0.f;                                                        \
      _Pragma("unroll") for (int k = 0; k < 8; ++k)                          \
          s_ += w[k] * reinterpret_cast<const float*>(&V[k])[i];             \
      s_ += __shfl_xor(s_, 8);                                               \
      s_ += __shfl_xor(s_, 16);                                              \
      s_ += __shfl_xor(s_, 32);                                              \
      sp[i] = s_;                                                            \
    }                                                                        \
    if (ln < 8) {                                                            \
      _Pragma("unroll") for (int i = 0; i < 4; ++i)                          \
          part[wv][ln * 4 + i] = sp[i];                                      \
    }                                                                        \
    lds_barrier();                                                           \
    {                                                                        \
      float q_ = 0.f;                                                        \
      if (t < NC) {                                                          \
        float s_ = 0.f;                                                      \
        _Pragma("unroll") for (int w8 = 0; w8 < 8; ++w8)                     \
            s_ += part[w8][t];                                               \
        const float h_ = 1.f / (1.f + __expf(-s_));                          \
        h_lds[t] = h_;                                                       \
        q_ = h_ * h_;                                                        \
        q_ += __shfl_xor(q_, 1);                                             \
        q_ += __shfl_xor(q_, 2);                                             \
        q_ += __shfl_xor(q_, 4);                                             \
        q_ += __shfl_xor(q_, 8);                                             \
        q_ += __shfl_xor(q_, 16);                                            \
      }                                                                      \
      if (t == 0) gacc += q_;                                                \
    }                                                                        \
    lds_barrier();                                                           \
    _Pragma("unroll") for (int i = 0; i < 4; ++i) {                          \
      const float hh = h_lds[jg * 4 + i];                                    \
      _Pragma("unroll") for (int k = 0; k < 8; ++k)                          \
          acc[k] += hh * reinterpret_cast<const float*>(&V[k])[i];           \
    }                                                                        \
  } while (0)

  LOADS(va, 0);     // slab 0 in flight
  LOADS(vb, 1);     // slab 1 in flight
  PROC(va);         // consume slab 0 (vmcnt waits leave slab 1 outstanding)
  LOADS(va, 2);     // slab 2 in flight
  PROC(vb);         // consume slab 1
  LOADS(vb, 3);     // slab 3 in flight
  PROC(va);         // consume slab 2
  PROC(vb);         // consume slab 3

#undef LOADS
#undef PROC

  // per-block xh partial: reduce over the 8 jg lanes sharing each z
#pragma unroll
  for (int k = 0; k < 8; ++k) {
    float a = acc[k];
    a += __shfl_xor(a, 1);
    a += __shfl_xor(a, 2);
    a += __shfl_xor(a, 4);
    if (jg == 0) pxh[(size_t)blk * Z_ + zr + 64 * k] = a;
  }
  if (t == 0) gws[blk] = gacc;
}

// out[b, z] = (sum_p pxh[b,p,z]) / (sum_p g[b,p] + LAM)
__global__ __launch_bounds__(Z_) void elm_k2(
    const float* __restrict__ pxh, const float* __restrict__ gws,
    float* __restrict__ out) {
  const int b = blockIdx.x;
  const int t = threadIdx.x;
  float g = LAM;
#pragma unroll
  for (int p = 0; p < PB; ++p) g += gws[b * PB + p];
  float s = 0.f;
#pragma unroll
  for (int p = 0; p < PB; ++p) s += pxh[((size_t)b * PB + p) * Z_ + t];
  out[b * Z_ + t] = s / g;
}

extern "C" void kernel_launch(void* const* d_in, const int* in_sizes, int n_in,
                              void* d_out, int out_size, void* d_ws, size_t ws_size,
                              hipStream_t stream) {
  const float* x  = (const float*)d_in[0];
  const float* Wh = (const float*)d_in[1];
  float* out = (float*)d_out;
  float* pxh = (float*)d_ws;            // B_*PB*Z_ floats = 1 MB
  float* gws = (float*)d_ws + WS_XH;    // B_*PB floats

  elm_k1<<<dim3(B_ * PB), dim3(TH), 0, stream>>>(x, Wh, pxh, gws);
  elm_k2<<<dim3(B_), dim3(Z_), 0, stream>>>(pxh, gws, out);
}